// Round 8
// baseline (506.694 us; speedup 1.0000x reference)
//
#include <hip/hip_runtime.h>
#include <math.h>

#define EPS_BN 1e-5f
#define MAXNB 512  // max coarse buckets (N <= 131072); also assumes N < 2^24

typedef __attribute__((ext_vector_type(8))) short bf16x8;
typedef __attribute__((ext_vector_type(4))) float f32x4;
typedef __attribute__((ext_vector_type(2))) float f32x2;

__device__ __forceinline__ ushort f2bf(float f) {
    uint u = __float_as_uint(f);
    u += 0x7FFF + ((u >> 16) & 1);  // RTN-even
    return (ushort)(u >> 16);
}
__device__ __forceinline__ float bf2f(uint h) {
    return __uint_as_float(h << 16);
}
__device__ __forceinline__ unsigned char f2fp8(float v) {
    uint q = __builtin_amdgcn_cvt_pk_fp8_f32(v, v, 0, false);
    return (unsigned char)(q & 0xff);
}

// ================= bucketed CSR build (fixed-stride buckets) =================
__global__ __launch_bounds__(512) void init_bcur_k(int* __restrict__ bcur, int NB,
                                                   int stride) {
    int t = threadIdx.x;
    if (t < NB) bcur[t] = t * stride;
}

// tile-ranked scatter; coarse entry packed: src | (dst&255)<<24
__global__ __launch_bounds__(256) void bucketA_k(const int* __restrict__ src,
                                                 const int* __restrict__ dst,
                                                 int* __restrict__ bcur,
                                                 int* __restrict__ coarse, int nE, int NB) {
    __shared__ int cnt[MAXNB];
    __shared__ int basix[MAXNB];
    const int tid = threadIdx.x;
    for (int i = tid; i < NB; i += 256) cnt[i] = 0;
    __syncthreads();
    int base = blockIdx.x * 4096;
    int es[16], ed[16], rk[16];
#pragma unroll
    for (int i = 0; i < 16; i++) {
        int e = base + i * 256 + tid;
        if (e < nE) {
            es[i] = src[e];
            ed[i] = dst[e];
            rk[i] = atomicAdd(&cnt[ed[i] >> 8], 1);
        } else {
            ed[i] = -1;
        }
    }
    __syncthreads();
    for (int i = tid; i < NB; i += 256)
        if (cnt[i]) basix[i] = atomicAdd(&bcur[i], cnt[i]);
    __syncthreads();
#pragma unroll
    for (int i = 0; i < 16; i++) {
        if (ed[i] >= 0)
            coarse[basix[ed[i] >> 8] + rk[i]] = es[i] | ((ed[i] & 255) << 24);
    }
}

// per-bucket exact CSR: rowstart/rowend/col/dinv; bucket b owns [b*stride, bcur[b])
__global__ __launch_bounds__(256) void bucketB_k(const int* __restrict__ coarse,
                                                 const int* __restrict__ bcur,
                                                 int* __restrict__ rowstart,
                                                 int* __restrict__ rowend,
                                                 int* __restrict__ col,
                                                 float* __restrict__ dinv, int N,
                                                 int stride) {
    __shared__ int cnt[256];
    __shared__ int s[256];
    __shared__ int cur[256];
    const int tid = threadIdx.x;
    const int b = blockIdx.x;
    const int beg = b * stride, end = bcur[b];
    cnt[tid] = 0;
    __syncthreads();
    for (int p = beg + tid; p < end; p += 256)
        atomicAdd(&cnt[((uint)coarse[p]) >> 24], 1);
    __syncthreads();
    int c = cnt[tid];
    s[tid] = c;
    __syncthreads();
    for (int off = 1; off < 256; off <<= 1) {
        int v = (tid >= off) ? s[tid - off] : 0;
        __syncthreads();
        s[tid] += v;
        __syncthreads();
    }
    int ex = s[tid] - c;
    int node = b * 256 + tid;
    if (node < N) {
        rowstart[node] = beg + ex;
        rowend[node] = beg + ex + c;
        dinv[node] = rsqrtf((float)c + 1.0f);  // +1 = self loop
    }
    cur[tid] = ex;
    __syncthreads();
    for (int p = beg + tid; p < end; p += 256) {
        int v = coarse[p];
        int r = atomicAdd(&cur[((uint)v) >> 24], 1);
        col[beg + r] = v & 0xFFFFFF;
    }
}

// ================= weight prep =================
__global__ __launch_bounds__(256) void prep_wt_all_k(const float* __restrict__ W1,
                                                     const float* __restrict__ W2,
                                                     const float* __restrict__ W3,
                                                     const float* __restrict__ W4,
                                                     ushort* __restrict__ T1,
                                                     ushort* __restrict__ T2,
                                                     ushort* __restrict__ T3,
                                                     ushort* __restrict__ T4) {
    int which = blockIdx.x >> 6;
    const float* W = (which == 0) ? W1 : (which == 1) ? W2 : (which == 2) ? W3 : W4;
    ushort* T = (which == 0) ? T1 : (which == 1) ? T2 : (which == 2) ? T3 : T4;
    int i = (blockIdx.x & 63) * 256 + threadIdx.x;  // < 16384
    int n = i >> 7, k = i & 127;
    T[n * 128 + k] = f2bf(W[k * 128 + n]);
}

// ============ shared gather core ============
// wave-wide: 16 lanes per edge-row (8 ch/lane), 4 edge-groups, 4-deep unroll
// returns BN'd+relu'd bf16-packed row chunk (valid in grp==0 lanes)
__device__ __forceinline__ void acc8_fp8(float* acc, uint2 a, float nn) {
    f32x2 p;
    p = __builtin_amdgcn_cvt_pk_f32_fp8(a.x, false);
    acc[0] = fmaf(p.x, nn, acc[0]); acc[1] = fmaf(p.y, nn, acc[1]);
    p = __builtin_amdgcn_cvt_pk_f32_fp8(a.x, true);
    acc[2] = fmaf(p.x, nn, acc[2]); acc[3] = fmaf(p.y, nn, acc[3]);
    p = __builtin_amdgcn_cvt_pk_f32_fp8(a.y, false);
    acc[4] = fmaf(p.x, nn, acc[4]); acc[5] = fmaf(p.y, nn, acc[5]);
    p = __builtin_amdgcn_cvt_pk_f32_fp8(a.y, true);
    acc[6] = fmaf(p.x, nn, acc[6]); acc[7] = fmaf(p.y, nn, acc[7]);
}

__device__ __forceinline__ uint4 gather_row(const unsigned char* __restrict__ h8,
                                            const int* __restrict__ col,
                                            const float* __restrict__ dinv,
                                            int node, int beg, int end, float dd,
                                            int grp, int c,
                                            const float* sc, const float* off) {
    float acc[8] = {0.f, 0.f, 0.f, 0.f, 0.f, 0.f, 0.f, 0.f};
    if (grp == 0) {  // self loop (outer dd applied at end)
        uint2 rv = *(const uint2*)&h8[(size_t)node * 128 + c];
        acc8_fp8(acc, rv, dd);
    }
    int p = beg + grp;
    for (; p + 12 < end; p += 16) {  // 4 edges per group per iter = 16 edges/wave
        int s0 = __builtin_nontemporal_load(col + p);
        int s1 = __builtin_nontemporal_load(col + p + 4);
        int s2 = __builtin_nontemporal_load(col + p + 8);
        int s3 = __builtin_nontemporal_load(col + p + 12);
        float n0 = dinv[s0], n1 = dinv[s1], n2 = dinv[s2], n3 = dinv[s3];
        uint2 a0 = *(const uint2*)&h8[(size_t)s0 * 128 + c];
        uint2 a1 = *(const uint2*)&h8[(size_t)s1 * 128 + c];
        uint2 a2 = *(const uint2*)&h8[(size_t)s2 * 128 + c];
        uint2 a3 = *(const uint2*)&h8[(size_t)s3 * 128 + c];
        acc8_fp8(acc, a0, n0);
        acc8_fp8(acc, a1, n1);
        acc8_fp8(acc, a2, n2);
        acc8_fp8(acc, a3, n3);
    }
    for (; p < end; p += 4) {
        int s0 = __builtin_nontemporal_load(col + p);
        float n0 = dinv[s0];
        uint2 a = *(const uint2*)&h8[(size_t)s0 * 128 + c];
        acc8_fp8(acc, a, n0);
    }
#pragma unroll
    for (int j = 0; j < 8; j++) {
        acc[j] += __shfl_xor(acc[j], 16, 64);
        acc[j] += __shfl_xor(acc[j], 32, 64);
    }
    uint r[4];
#pragma unroll
    for (int j = 0; j < 4; j++) {
        float o0 = fmaxf(acc[j * 2] * dd * sc[j * 2] + off[j * 2], 0.0f);
        float o1 = fmaxf(acc[j * 2 + 1] * dd * sc[j * 2 + 1] + off[j * 2 + 1], 0.0f);
        r[j] = (uint)f2bf(o0) | ((uint)f2bf(o1) << 16);
    }
    return (uint4){r[0], r[1], r[2], r[3]};
}

// ============ standalone gather conv (layer 1): fp8 h -> bf16 out ============
__global__ __launch_bounds__(256) void gather_k(const unsigned char* __restrict__ h8,
                                                const int* __restrict__ rowstart,
                                                const int* __restrict__ rowend,
                                                const int* __restrict__ col,
                                                const float* __restrict__ dinv,
                                                const float* __restrict__ bias,
                                                const float* __restrict__ g,
                                                const float* __restrict__ be,
                                                const float* __restrict__ mn,
                                                const float* __restrict__ vr,
                                                ushort* __restrict__ out, int n) {
    int node = blockIdx.x * 4 + (threadIdx.x >> 6);
    if (node >= n) return;
    int lane = threadIdx.x & 63;
    int grp = lane >> 4, li = lane & 15;
    int c = li * 8;
    float sc[8], offc[8];
#pragma unroll
    for (int j = 0; j < 8; j++) {
        float s = g[c + j] * rsqrtf(vr[c + j] + EPS_BN);
        sc[j] = s;
        offc[j] = (bias[c + j] - mn[c + j]) * s + be[c + j];
    }
    int beg = rowstart[node], end = rowend[node];
    float dd = dinv[node];
    uint4 rv = gather_row(h8, col, dinv, node, beg, end, dd, grp, c, sc, offc);
    if (grp == 0) *(uint4*)&out[(size_t)node * 128 + c] = rv;
}

// ============ fused conv2-gather + GEMM3 ============
// per 64-node tile: gather conv2 rows (BN2+relu, bf16) into LDS, then
// Y = relu(bn3(Xg @ Wt + bf1)) -> bf16
__global__ __launch_bounds__(256) void fused_conv_gemm_k(
    const unsigned char* __restrict__ h8, const int* __restrict__ rowstart,
    const int* __restrict__ rowend, const int* __restrict__ col,
    const float* __restrict__ dinv, const float* __restrict__ cbias,
    const float* __restrict__ cg, const float* __restrict__ cbe,
    const float* __restrict__ cmn, const float* __restrict__ cvr,
    const ushort* __restrict__ Wt, const float* __restrict__ bias,
    const float* __restrict__ g, const float* __restrict__ be,
    const float* __restrict__ mn, const float* __restrict__ vr,
    ushort* __restrict__ Y, int nrows) {
    constexpr int LDK = 136;
    __shared__ ushort sX[64 * LDK];
    __shared__ ushort sW[128 * LDK];
    const int tid = threadIdx.x;
    const int row0 = blockIdx.x * 64;

    // stage W (no barrier needed until MFMA)
#pragma unroll
    for (int i = 0; i < 8; i++) {
        int cc = tid + i * 256;
        int r = cc >> 4, o = cc & 15;
        *(int4*)&sW[r * LDK + o * 8] = *(const int4*)&Wt[r * 128 + o * 8];
    }

    const int wave = tid >> 6, lane = tid & 63;
    const int grp = lane >> 4, li = lane & 15;
    const int c = li * 8;
    float sc[8], offc[8];
#pragma unroll
    for (int j = 0; j < 8; j++) {
        float s = cg[c + j] * rsqrtf(cvr[c + j] + EPS_BN);
        sc[j] = s;
        offc[j] = (cbias[c + j] - cmn[c + j]) * s + cbe[c + j];
    }
    // gather phase: wave w handles local rows w*16 .. w*16+15
    for (int i = 0; i < 16; i++) {
        int lr = wave * 16 + i;
        int node = row0 + lr;
        if (node >= nrows) break;
        int beg = rowstart[node], end = rowend[node];
        float dd = dinv[node];
        uint4 rv = gather_row(h8, col, dinv, node, beg, end, dd, grp, c, sc, offc);
        if (grp == 0) *(uint4*)&sX[lr * LDK + c] = rv;
    }
    __syncthreads();

    const int rw = (wave >> 1) * 32;
    const int cw = (wave & 1) * 64;
    const int lm = lane & 15, lq = lane >> 4;

    f32x4 acc[2][4];
#pragma unroll
    for (int tr = 0; tr < 2; tr++)
#pragma unroll
        for (int tc = 0; tc < 4; tc++) acc[tr][tc] = (f32x4){0.f, 0.f, 0.f, 0.f};

#pragma unroll
    for (int ks = 0; ks < 4; ks++) {
        int kb = ks * 32 + lq * 8;
        bf16x8 a[2], b[4];
#pragma unroll
        for (int tr = 0; tr < 2; tr++)
            a[tr] = *(bf16x8*)&sX[(rw + tr * 16 + lm) * LDK + kb];
#pragma unroll
        for (int tc = 0; tc < 4; tc++)
            b[tc] = *(bf16x8*)&sW[(cw + tc * 16 + lm) * LDK + kb];
#pragma unroll
        for (int tr = 0; tr < 2; tr++)
#pragma unroll
            for (int tc = 0; tc < 4; tc++)
                acc[tr][tc] = __builtin_amdgcn_mfma_f32_16x16x32_bf16(a[tr], b[tc],
                                                                      acc[tr][tc], 0, 0, 0);
    }

#pragma unroll
    for (int tc = 0; tc < 4; tc++) {
        int cc = cw + tc * 16 + lm;
        float s = g[cc] * rsqrtf(vr[cc] + EPS_BN);
        float psh = be[cc] + (bias[cc] - mn[cc]) * s;
#pragma unroll
        for (int tr = 0; tr < 2; tr++) {
#pragma unroll
            for (int r = 0; r < 4; r++) {
                int row = row0 + rw + tr * 16 + lq * 4 + r;
                if (row < nrows) {
                    float v = fmaxf(acc[tr][tc][r] * s + psh, 0.0f);
                    Y[(size_t)row * 128 + cc] = f2bf(v);
                }
            }
        }
    }
}

// ============ MFMA GEMM: Y = X(n,128) @ W(128,128), fused epilogues ============
// MODE 0: raw -> fp8 e4m3   MODE 2: relu(v+bias) -> f32 + head softplus(h1@Wo+bo)
// F32IN: input X is f32 (converted to bf16 during LDS staging)
template <int MODE, int F32IN>
__global__ __launch_bounds__(256) void mfma_gemm_k(const void* __restrict__ Xin,
                                                   const ushort* __restrict__ Wt,
                                                   const float* __restrict__ bias,
                                                   const float* __restrict__ Wo,
                                                   const float* __restrict__ bo,
                                                   float* __restrict__ pred,
                                                   void* __restrict__ Y, int nrows) {
    constexpr int LDK = 136;
    __shared__ ushort sX[64 * LDK];
    __shared__ ushort sW[128 * LDK];
    __shared__ float red[64];
    const int tid = threadIdx.x;
    const int row0 = blockIdx.x * 64;

#pragma unroll
    for (int i = 0; i < 8; i++) {
        int c = tid + i * 256;
        int r = c >> 4, o = c & 15;
        *(int4*)&sW[r * LDK + o * 8] = *(const int4*)&Wt[r * 128 + o * 8];
    }
    if (F32IN) {
        const float* Xf = (const float*)Xin;
#pragma unroll
        for (int i = 0; i < 8; i++) {
            int c = tid + i * 256;
            int r = c >> 5, o = c & 31;
            int rg = row0 + r;
            if (rg >= nrows) rg = nrows - 1;
            float4 v = *(const float4*)&Xf[(size_t)rg * 128 + o * 4];
            ushort4 u = {f2bf(v.x), f2bf(v.y), f2bf(v.z), f2bf(v.w)};
            *(ushort4*)&sX[r * LDK + o * 4] = u;
        }
    } else {
        const ushort* Xb = (const ushort*)Xin;
#pragma unroll
        for (int i = 0; i < 4; i++) {
            int c = tid + i * 256;
            int r = c >> 4, o = c & 15;
            int rg = row0 + r;
            if (rg >= nrows) rg = nrows - 1;
            *(int4*)&sX[r * LDK + o * 8] = *(const int4*)&Xb[(size_t)rg * 128 + o * 8];
        }
    }
    if (MODE == 2 && tid < 64) red[tid] = 0.0f;
    __syncthreads();

    const int wave = tid >> 6, lane = tid & 63;
    const int rw = (wave >> 1) * 32;
    const int cw = (wave & 1) * 64;
    const int lm = lane & 15, lq = lane >> 4;

    f32x4 acc[2][4];
#pragma unroll
    for (int tr = 0; tr < 2; tr++)
#pragma unroll
        for (int tc = 0; tc < 4; tc++) acc[tr][tc] = (f32x4){0.f, 0.f, 0.f, 0.f};

#pragma unroll
    for (int ks = 0; ks < 4; ks++) {
        int kb = ks * 32 + lq * 8;
        bf16x8 a[2], b[4];
#pragma unroll
        for (int tr = 0; tr < 2; tr++)
            a[tr] = *(bf16x8*)&sX[(rw + tr * 16 + lm) * LDK + kb];
#pragma unroll
        for (int tc = 0; tc < 4; tc++)
            b[tc] = *(bf16x8*)&sW[(cw + tc * 16 + lm) * LDK + kb];
#pragma unroll
        for (int tr = 0; tr < 2; tr++)
#pragma unroll
            for (int tc = 0; tc < 4; tc++)
                acc[tr][tc] = __builtin_amdgcn_mfma_f32_16x16x32_bf16(a[tr], b[tc],
                                                                      acc[tr][tc], 0, 0, 0);
    }

    float part[8];
    if (MODE == 2) {
#pragma unroll
        for (int i = 0; i < 8; i++) part[i] = 0.0f;
    }
#pragma unroll
    for (int tc = 0; tc < 4; tc++) {
        int c = cw + tc * 16 + lm;
        float psh = (MODE == 2) ? bias[c] : 0.0f;
        float woc = (MODE == 2) ? Wo[c] : 0.0f;
#pragma unroll
        for (int tr = 0; tr < 2; tr++) {
#pragma unroll
            for (int r = 0; r < 4; r++) {
                int row = row0 + rw + tr * 16 + lq * 4 + r;
                if (row < nrows) {
                    float v = acc[tr][tc][r];
                    if (MODE == 0) {
                        ((unsigned char*)Y)[(size_t)row * 128 + c] = f2fp8(v);
                    } else {
                        v = fmaxf(v + psh, 0.0f);
                        ((float*)Y)[(size_t)row * 128 + c] = v;
                        part[tr * 4 + r] = fmaf(v, woc, part[tr * 4 + r]);
                    }
                }
            }
        }
    }
    if (MODE == 2) {
#pragma unroll
        for (int tr = 0; tr < 2; tr++)
#pragma unroll
            for (int r = 0; r < 4; r++)
                atomicAdd(&red[rw + tr * 16 + lq * 4 + r], part[tr * 4 + r]);
        __syncthreads();
        if (tid < 64) {
            int row = row0 + tid;
            if (row < nrows) {
                float xv = red[tid] + bo[0];
                pred[row] = fmaxf(xv, 0.0f) + log1pf(expf(-fabsf(xv)));  // softplus
            }
        }
    }
}

extern "C" void kernel_launch(void* const* d_in, const int* in_sizes, int n_in,
                              void* d_out, int out_size, void* d_ws, size_t ws_size,
                              hipStream_t stream) {
    const float* x = (const float*)d_in[0];
    const int* ei = (const int*)d_in[1];
    const int N = in_sizes[0] / 128;
    const int E = in_sizes[1] / 2;
    const int* srcv = ei;
    const int* dstv = ei + E;
    const float* W1 = (const float*)d_in[2];  const float* b1 = (const float*)d_in[3];
    const float* W2 = (const float*)d_in[4];  const float* b2 = (const float*)d_in[5];
    const float* Wf1 = (const float*)d_in[6]; const float* bf1 = (const float*)d_in[7];
    const float* Wf2 = (const float*)d_in[8]; const float* bf2 = (const float*)d_in[9];
    const float* Wo = (const float*)d_in[10]; const float* bo = (const float*)d_in[11];
    const float* g1 = (const float*)d_in[12], *be1 = (const float*)d_in[13],
               *m1 = (const float*)d_in[14], *v1 = (const float*)d_in[15];
    const float* g2 = (const float*)d_in[16], *be2 = (const float*)d_in[17],
               *m2 = (const float*)d_in[18], *v2 = (const float*)d_in[19];
    const float* g3 = (const float*)d_in[20], *be3 = (const float*)d_in[21],
               *m3 = (const float*)d_in[22], *v3 = (const float*)d_in[23];

    // ---- workspace carve-up ----
    char* ws = (char*)d_ws;
    size_t off = 0;
    auto carve = [&](size_t bytes) {
        char* p = ws + off;
        off = (off + bytes + 255) & ~(size_t)255;
        return p;
    };
    const int NB = (N + 255) >> 8;
    const int STRIDE = ((E / NB + 511) + 255) & ~255;  // mean + ~6 sigma slack
    int* bcur = (int*)carve((size_t)MAXNB * 4);
    int* rowstart = (int*)carve((size_t)N * 4);
    int* rowend = (int*)carve((size_t)N * 4);
    int* col = (int*)carve((size_t)NB * STRIDE * 4);
    int* coarse = (int*)carve((size_t)NB * STRIDE * 4);
    float* dinv = (float*)carve((size_t)N * 4);
    unsigned char* bufA8 = (unsigned char*)carve((size_t)N * 128);  // fp8 h
    ushort* bufB = (ushort*)carve((size_t)N * 128 * 2);             // bf16
    ushort* bufC = (ushort*)carve((size_t)N * 128 * 2);             // bf16
    ushort* Wt1 = (ushort*)carve(128 * 128 * 2);
    ushort* Wt2 = (ushort*)carve(128 * 128 * 2);
    ushort* Wtf1 = (ushort*)carve(128 * 128 * 2);
    ushort* Wtf2 = (ushort*)carve(128 * 128 * 2);

    float* out_pred = (float*)d_out;
    float* out_h1 = out_pred + N;

    const int gblocks = (N + 63) / 64;
    const int tblocks = (E + 4095) / 4096;
    const int wblocks = (N + 3) / 4;

    // ---- CSR build ----
    init_bcur_k<<<1, 512, 0, stream>>>(bcur, NB, STRIDE);
    bucketA_k<<<tblocks, 256, 0, stream>>>(srcv, dstv, bcur, coarse, E, NB);
    bucketB_k<<<NB, 256, 0, stream>>>(coarse, bcur, rowstart, rowend, col, dinv, N,
                                      STRIDE);

    // ---- weight prep ----
    prep_wt_all_k<<<256, 256, 0, stream>>>(W1, W2, Wf1, Wf2, Wt1, Wt2, Wtf1, Wtf2);

    // layer 1: h = x@W1 (fp8)
    mfma_gemm_k<0, 1><<<gblocks, 256, 0, stream>>>(x, Wt1, nullptr, nullptr, nullptr,
                                                   nullptr, bufA8, N);
    // conv1 + bn1 + relu -> bf16
    gather_k<<<wblocks, 256, 0, stream>>>(bufA8, rowstart, rowend, col, dinv, b1, g1,
                                          be1, m1, v1, bufB, N);
    // layer 2 GEMM: h@W2 (fp8)
    mfma_gemm_k<0, 0><<<gblocks, 256, 0, stream>>>(bufB, Wt2, nullptr, nullptr, nullptr,
                                                   nullptr, bufA8, N);
    // fused: conv2+bn2+relu (gather) -> LDS -> GEMM3: relu(bn3(. @Wf1 + bf1)) -> bf16
    fused_conv_gemm_k<<<gblocks, 256, 0, stream>>>(bufA8, rowstart, rowend, col, dinv,
                                                   b2, g2, be2, m2, v2, Wtf1, bf1, g3,
                                                   be3, m3, v3, bufC, N);
    // layer 4 + head: h1 = relu(h@Wf2 + bf2) -> f32 d_out; pred = softplus(h1@Wo+bo)
    mfma_gemm_k<2, 0><<<gblocks, 256, 0, stream>>>(bufC, Wtf2, bf2, Wo, bo, out_pred,
                                                   out_h1, N);
}

// Round 9
// 457.148 us; speedup vs baseline: 1.1084x; 1.1084x over previous
//
#include <hip/hip_runtime.h>
#include <math.h>

#define EPS_BN 1e-5f
#define MAXNB 512  // max coarse buckets (N <= 131072); also assumes N < 2^24

typedef __attribute__((ext_vector_type(8))) short bf16x8;
typedef __attribute__((ext_vector_type(4))) float f32x4;
typedef __attribute__((ext_vector_type(2))) float f32x2;

__device__ __forceinline__ ushort f2bf(float f) {
    uint u = __float_as_uint(f);
    u += 0x7FFF + ((u >> 16) & 1);  // RTN-even
    return (ushort)(u >> 16);
}
__device__ __forceinline__ float bf2f(uint h) {
    return __uint_as_float(h << 16);
}
__device__ __forceinline__ unsigned char f2fp8(float v) {
    uint q = __builtin_amdgcn_cvt_pk_fp8_f32(v, v, 0, false);
    return (unsigned char)(q & 0xff);
}

// ================= prep: 4 weight transposes (f32->bf16^T) + bcur init =================
__global__ __launch_bounds__(256) void prep_k(const float* __restrict__ W1,
                                              const float* __restrict__ W2,
                                              const float* __restrict__ W3,
                                              const float* __restrict__ W4,
                                              ushort* __restrict__ T1,
                                              ushort* __restrict__ T2,
                                              ushort* __restrict__ T3,
                                              ushort* __restrict__ T4,
                                              int* __restrict__ bcur, int NB, int stride) {
    if (blockIdx.x == 256) {
        for (int i = threadIdx.x; i < NB; i += 256) bcur[i] = i * stride;
        return;
    }
    int which = blockIdx.x >> 6;
    const float* W = (which == 0) ? W1 : (which == 1) ? W2 : (which == 2) ? W3 : W4;
    ushort* T = (which == 0) ? T1 : (which == 1) ? T2 : (which == 2) ? T3 : T4;
    int i = (blockIdx.x & 63) * 256 + threadIdx.x;  // < 16384
    int n = i >> 7, k = i & 127;
    T[n * 128 + k] = f2bf(W[k * 128 + n]);
}

// ================= bucketed CSR build (fixed-stride buckets) =================
// tile-ranked scatter; coarse entry packed: src | (dst&255)<<24
__global__ __launch_bounds__(256) void bucketA_k(const int* __restrict__ src,
                                                 const int* __restrict__ dst,
                                                 int* __restrict__ bcur,
                                                 int* __restrict__ coarse, int nE, int NB) {
    __shared__ int cnt[MAXNB];
    __shared__ int basix[MAXNB];
    const int tid = threadIdx.x;
    for (int i = tid; i < NB; i += 256) cnt[i] = 0;
    __syncthreads();
    int base = blockIdx.x * 4096;
    int es[16], ed[16], rk[16];
#pragma unroll
    for (int i = 0; i < 16; i++) {
        int e = base + i * 256 + tid;
        if (e < nE) {
            es[i] = src[e];
            ed[i] = dst[e];
            rk[i] = atomicAdd(&cnt[ed[i] >> 8], 1);
        } else {
            ed[i] = -1;
        }
    }
    __syncthreads();
    for (int i = tid; i < NB; i += 256)
        if (cnt[i]) basix[i] = atomicAdd(&bcur[i], cnt[i]);
    __syncthreads();
#pragma unroll
    for (int i = 0; i < 16; i++) {
        if (ed[i] >= 0)
            coarse[basix[ed[i] >> 8] + rk[i]] = es[i] | ((ed[i] & 255) << 24);
    }
}

// per-bucket exact CSR: rowstart/rowend/col/dinv; bucket b owns [b*stride, bcur[b])
__global__ __launch_bounds__(256) void bucketB_k(const int* __restrict__ coarse,
                                                 const int* __restrict__ bcur,
                                                 int* __restrict__ rowstart,
                                                 int* __restrict__ rowend,
                                                 int* __restrict__ col,
                                                 float* __restrict__ dinv, int N,
                                                 int stride) {
    __shared__ int cnt[256];
    __shared__ int s[256];
    __shared__ int cur[256];
    const int tid = threadIdx.x;
    const int b = blockIdx.x;
    const int beg = b * stride, end = bcur[b];
    cnt[tid] = 0;
    __syncthreads();
    for (int p = beg + tid; p < end; p += 256)
        atomicAdd(&cnt[((uint)coarse[p]) >> 24], 1);
    __syncthreads();
    int c = cnt[tid];
    s[tid] = c;
    __syncthreads();
    for (int off = 1; off < 256; off <<= 1) {
        int v = (tid >= off) ? s[tid - off] : 0;
        __syncthreads();
        s[tid] += v;
        __syncthreads();
    }
    int ex = s[tid] - c;
    int node = b * 256 + tid;
    if (node < N) {
        rowstart[node] = beg + ex;
        rowend[node] = beg + ex + c;
        dinv[node] = rsqrtf((float)c + 1.0f);  // +1 = self loop
    }
    cur[tid] = ex;
    __syncthreads();
    for (int p = beg + tid; p < end; p += 256) {
        int v = coarse[p];
        int r = atomicAdd(&cur[((uint)v) >> 24], 1);
        col[beg + r] = v & 0xFFFFFF;
    }
}

// ============ gather conv over fp8 h rows ============
// out = relu(bn(dd*(dd*h[d] + Sum_s dinv[s]*h[s]) + bias))
// 8 lanes per edge-row (16 ch/lane, uint4 = 16B), 8 edge-groups, 4-deep unroll
// => 32 edges in flight per wave
__device__ __forceinline__ void acc16_fp8(float* acc, uint4 a, float nn) {
    f32x2 p;
    p = __builtin_amdgcn_cvt_pk_f32_fp8(a.x, false);
    acc[0] = fmaf(p.x, nn, acc[0]);  acc[1] = fmaf(p.y, nn, acc[1]);
    p = __builtin_amdgcn_cvt_pk_f32_fp8(a.x, true);
    acc[2] = fmaf(p.x, nn, acc[2]);  acc[3] = fmaf(p.y, nn, acc[3]);
    p = __builtin_amdgcn_cvt_pk_f32_fp8(a.y, false);
    acc[4] = fmaf(p.x, nn, acc[4]);  acc[5] = fmaf(p.y, nn, acc[5]);
    p = __builtin_amdgcn_cvt_pk_f32_fp8(a.y, true);
    acc[6] = fmaf(p.x, nn, acc[6]);  acc[7] = fmaf(p.y, nn, acc[7]);
    p = __builtin_amdgcn_cvt_pk_f32_fp8(a.z, false);
    acc[8] = fmaf(p.x, nn, acc[8]);  acc[9] = fmaf(p.y, nn, acc[9]);
    p = __builtin_amdgcn_cvt_pk_f32_fp8(a.z, true);
    acc[10] = fmaf(p.x, nn, acc[10]); acc[11] = fmaf(p.y, nn, acc[11]);
    p = __builtin_amdgcn_cvt_pk_f32_fp8(a.w, false);
    acc[12] = fmaf(p.x, nn, acc[12]); acc[13] = fmaf(p.y, nn, acc[13]);
    p = __builtin_amdgcn_cvt_pk_f32_fp8(a.w, true);
    acc[14] = fmaf(p.x, nn, acc[14]); acc[15] = fmaf(p.y, nn, acc[15]);
}

__global__ __launch_bounds__(256) void gather_k(const unsigned char* __restrict__ h8,
                                                const int* __restrict__ rowstart,
                                                const int* __restrict__ rowend,
                                                const int* __restrict__ col,
                                                const float* __restrict__ dinv,
                                                const float* __restrict__ bias,
                                                const float* __restrict__ g,
                                                const float* __restrict__ be,
                                                const float* __restrict__ mn,
                                                const float* __restrict__ vr,
                                                ushort* __restrict__ out, int n) {
    int node = blockIdx.x * 4 + (threadIdx.x >> 6);
    if (node >= n) return;
    int lane = threadIdx.x & 63;
    int grp = lane >> 3;   // 0..7: edge slot
    int li = lane & 7;     // channel group: 16 ch
    int c = li * 16;
    int beg = rowstart[node], end = rowend[node];
    float dd = dinv[node];
    float acc[16];
#pragma unroll
    for (int j = 0; j < 16; j++) acc[j] = 0.0f;

    if (grp == 0) {  // self loop
        uint4 rv = *(const uint4*)&h8[(size_t)node * 128 + c];
        acc16_fp8(acc, rv, dd);
    }

    int p = beg + grp;
    for (; p + 24 < end; p += 32) {  // 4 edges per group per iter = 32 edges/wave
        int s0 = __builtin_nontemporal_load(col + p);
        int s1 = __builtin_nontemporal_load(col + p + 8);
        int s2 = __builtin_nontemporal_load(col + p + 16);
        int s3 = __builtin_nontemporal_load(col + p + 24);
        float n0 = dinv[s0], n1 = dinv[s1], n2 = dinv[s2], n3 = dinv[s3];
        uint4 a0 = *(const uint4*)&h8[(size_t)s0 * 128 + c];
        uint4 a1 = *(const uint4*)&h8[(size_t)s1 * 128 + c];
        uint4 a2 = *(const uint4*)&h8[(size_t)s2 * 128 + c];
        uint4 a3 = *(const uint4*)&h8[(size_t)s3 * 128 + c];
        acc16_fp8(acc, a0, n0);
        acc16_fp8(acc, a1, n1);
        acc16_fp8(acc, a2, n2);
        acc16_fp8(acc, a3, n3);
    }
    for (; p < end; p += 8) {
        int s0 = __builtin_nontemporal_load(col + p);
        float n0 = dinv[s0];
        uint4 a = *(const uint4*)&h8[(size_t)s0 * 128 + c];
        acc16_fp8(acc, a, n0);
    }
    // reduce the 8 edge-groups (lanes li, li+8, ..., li+56 hold same channels)
#pragma unroll
    for (int j = 0; j < 16; j++) {
        acc[j] += __shfl_xor(acc[j], 8, 64);
        acc[j] += __shfl_xor(acc[j], 16, 64);
        acc[j] += __shfl_xor(acc[j], 32, 64);
    }
    if (grp == 0) {
        uint r[8];
#pragma unroll
        for (int j = 0; j < 8; j++) {
            int cc = c + j * 2;
            float sc0 = g[cc] * rsqrtf(vr[cc] + EPS_BN);
            float sc1 = g[cc + 1] * rsqrtf(vr[cc + 1] + EPS_BN);
            float o0 = fmaxf((acc[j * 2] * dd + bias[cc] - mn[cc]) * sc0 + be[cc], 0.0f);
            float o1 = fmaxf((acc[j * 2 + 1] * dd + bias[cc + 1] - mn[cc + 1]) * sc1 + be[cc + 1], 0.0f);
            r[j] = (uint)f2bf(o0) | ((uint)f2bf(o1) << 16);
        }
        uint4 rv0 = {r[0], r[1], r[2], r[3]};
        uint4 rv1 = {r[4], r[5], r[6], r[7]};
        *(uint4*)&out[(size_t)node * 128 + c] = rv0;
        *(uint4*)&out[(size_t)node * 128 + c + 8] = rv1;
    }
}

// ============ MFMA GEMM: Y = X(n,128) @ W(128,128), fused epilogues ============
// MODE 0: raw -> fp8 e4m3   MODE 1: relu(bn(v+bias)) -> bf16
// MODE 2: relu(v+bias) -> f32, PLUS fused head: pred = softplus(h1 @ Wo + bo)
// F32IN: input X is f32 (converted to bf16 during LDS staging)
template <int MODE, int F32IN>
__global__ __launch_bounds__(256) void mfma_gemm_k(const void* __restrict__ Xin,
                                                   const ushort* __restrict__ Wt,
                                                   const float* __restrict__ bias,
                                                   const float* __restrict__ g,
                                                   const float* __restrict__ be,
                                                   const float* __restrict__ mn,
                                                   const float* __restrict__ vr,
                                                   const float* __restrict__ Wo,
                                                   const float* __restrict__ bo,
                                                   float* __restrict__ pred,
                                                   void* __restrict__ Y, int nrows) {
    constexpr int LDK = 136;  // 128 + 8 pad
    __shared__ ushort sX[64 * LDK];
    __shared__ ushort sW[128 * LDK];
    __shared__ float red[64];
    const int tid = threadIdx.x;
    const int row0 = blockIdx.x * 64;

#pragma unroll
    for (int i = 0; i < 8; i++) {
        int c = tid + i * 256;
        int r = c >> 4, o = c & 15;
        *(int4*)&sW[r * LDK + o * 8] = *(const int4*)&Wt[r * 128 + o * 8];
    }
    if (F32IN) {
        const float* Xf = (const float*)Xin;
#pragma unroll
        for (int i = 0; i < 8; i++) {
            int c = tid + i * 256;
            int r = c >> 5, o = c & 31;
            int rg = row0 + r;
            if (rg >= nrows) rg = nrows - 1;
            float4 v = *(const float4*)&Xf[(size_t)rg * 128 + o * 4];
            ushort4 u = {f2bf(v.x), f2bf(v.y), f2bf(v.z), f2bf(v.w)};
            *(ushort4*)&sX[r * LDK + o * 4] = u;
        }
    } else {
        const ushort* Xb = (const ushort*)Xin;
#pragma unroll
        for (int i = 0; i < 4; i++) {
            int c = tid + i * 256;
            int r = c >> 4, o = c & 15;
            int rg = row0 + r;
            if (rg >= nrows) rg = nrows - 1;
            *(int4*)&sX[r * LDK + o * 8] = *(const int4*)&Xb[(size_t)rg * 128 + o * 8];
        }
    }
    if (MODE == 2 && tid < 64) red[tid] = 0.0f;
    __syncthreads();

    const int wave = tid >> 6, lane = tid & 63;
    const int rw = (wave >> 1) * 32;
    const int cw = (wave & 1) * 64;
    const int lm = lane & 15, lq = lane >> 4;

    f32x4 acc[2][4];
#pragma unroll
    for (int tr = 0; tr < 2; tr++)
#pragma unroll
        for (int tc = 0; tc < 4; tc++) acc[tr][tc] = (f32x4){0.f, 0.f, 0.f, 0.f};

#pragma unroll
    for (int ks = 0; ks < 4; ks++) {
        int kb = ks * 32 + lq * 8;
        bf16x8 a[2], b[4];
#pragma unroll
        for (int tr = 0; tr < 2; tr++)
            a[tr] = *(bf16x8*)&sX[(rw + tr * 16 + lm) * LDK + kb];
#pragma unroll
        for (int tc = 0; tc < 4; tc++)
            b[tc] = *(bf16x8*)&sW[(cw + tc * 16 + lm) * LDK + kb];
#pragma unroll
        for (int tr = 0; tr < 2; tr++)
#pragma unroll
            for (int tc = 0; tc < 4; tc++)
                acc[tr][tc] = __builtin_amdgcn_mfma_f32_16x16x32_bf16(a[tr], b[tc],
                                                                      acc[tr][tc], 0, 0, 0);
    }

    float part[8];
    if (MODE == 2) {
#pragma unroll
        for (int i = 0; i < 8; i++) part[i] = 0.0f;
    }
#pragma unroll
    for (int tc = 0; tc < 4; tc++) {
        int c = cw + tc * 16 + lm;
        float psc, psh;
        if (MODE == 1) {
            float sc = g[c] * rsqrtf(vr[c] + EPS_BN);
            psc = sc;
            psh = be[c] + (bias[c] - mn[c]) * sc;
        } else if (MODE == 2) {
            psc = 1.0f;
            psh = bias[c];
        } else {
            psc = 1.0f;
            psh = 0.0f;
        }
        float woc = (MODE == 2) ? Wo[c] : 0.0f;
#pragma unroll
        for (int tr = 0; tr < 2; tr++) {
#pragma unroll
            for (int r = 0; r < 4; r++) {
                int row = row0 + rw + tr * 16 + lq * 4 + r;
                if (row < nrows) {
                    float v = acc[tr][tc][r];
                    if (MODE == 0) {
                        ((unsigned char*)Y)[(size_t)row * 128 + c] = f2fp8(v);
                    } else if (MODE == 1) {
                        v = fmaxf(v * psc + psh, 0.0f);
                        ((ushort*)Y)[(size_t)row * 128 + c] = f2bf(v);
                    } else {
                        v = fmaxf(v + psh, 0.0f);
                        ((float*)Y)[(size_t)row * 128 + c] = v;
                        part[tr * 4 + r] = fmaf(v, woc, part[tr * 4 + r]);
                    }
                }
            }
        }
    }
    if (MODE == 2) {
#pragma unroll
        for (int tr = 0; tr < 2; tr++)
#pragma unroll
            for (int r = 0; r < 4; r++)
                atomicAdd(&red[rw + tr * 16 + lq * 4 + r], part[tr * 4 + r]);
        __syncthreads();
        if (tid < 64) {
            int row = row0 + tid;
            if (row < nrows) {
                float xv = red[tid] + bo[0];
                pred[row] = fmaxf(xv, 0.0f) + log1pf(expf(-fabsf(xv)));  // softplus
            }
        }
    }
}

extern "C" void kernel_launch(void* const* d_in, const int* in_sizes, int n_in,
                              void* d_out, int out_size, void* d_ws, size_t ws_size,
                              hipStream_t stream) {
    const float* x = (const float*)d_in[0];
    const int* ei = (const int*)d_in[1];
    const int N = in_sizes[0] / 128;
    const int E = in_sizes[1] / 2;
    const int* srcv = ei;
    const int* dstv = ei + E;
    const float* W1 = (const float*)d_in[2];  const float* b1 = (const float*)d_in[3];
    const float* W2 = (const float*)d_in[4];  const float* b2 = (const float*)d_in[5];
    const float* Wf1 = (const float*)d_in[6]; const float* bf1 = (const float*)d_in[7];
    const float* Wf2 = (const float*)d_in[8]; const float* bf2 = (const float*)d_in[9];
    const float* Wo = (const float*)d_in[10]; const float* bo = (const float*)d_in[11];
    const float* g1 = (const float*)d_in[12], *be1 = (const float*)d_in[13],
               *m1 = (const float*)d_in[14], *v1 = (const float*)d_in[15];
    const float* g2 = (const float*)d_in[16], *be2 = (const float*)d_in[17],
               *m2 = (const float*)d_in[18], *v2 = (const float*)d_in[19];
    const float* g3 = (const float*)d_in[20], *be3 = (const float*)d_in[21],
               *m3 = (const float*)d_in[22], *v3 = (const float*)d_in[23];

    // ---- workspace carve-up ----
    char* ws = (char*)d_ws;
    size_t off = 0;
    auto carve = [&](size_t bytes) {
        char* p = ws + off;
        off = (off + bytes + 255) & ~(size_t)255;
        return p;
    };
    const int NB = (N + 255) >> 8;
    const int STRIDE = ((E / NB + 511) + 255) & ~255;  // mean + ~8 sigma slack
    int* bcur = (int*)carve((size_t)MAXNB * 4);
    int* rowstart = (int*)carve((size_t)N * 4);
    int* rowend = (int*)carve((size_t)N * 4);
    int* col = (int*)carve((size_t)NB * STRIDE * 4);
    int* coarse = (int*)carve((size_t)NB * STRIDE * 4);
    float* dinv = (float*)carve((size_t)N * 4);
    unsigned char* bufA8 = (unsigned char*)carve((size_t)N * 128);  // fp8 h
    ushort* bufB = (ushort*)carve((size_t)N * 128 * 2);             // bf16
    ushort* bufC = (ushort*)carve((size_t)N * 128 * 2);             // bf16
    ushort* Wt1 = (ushort*)carve(128 * 128 * 2);
    ushort* Wt2 = (ushort*)carve(128 * 128 * 2);
    ushort* Wtf1 = (ushort*)carve(128 * 128 * 2);
    ushort* Wtf2 = (ushort*)carve(128 * 128 * 2);

    float* out_pred = (float*)d_out;
    float* out_h1 = out_pred + N;

    const int gblocks = (N + 63) / 64;
    const int tblocks = (E + 4095) / 4096;
    const int wblocks = (N + 3) / 4;

    // ---- prep (weights + bcur) ----
    prep_k<<<257, 256, 0, stream>>>(W1, W2, Wf1, Wf2, Wt1, Wt2, Wtf1, Wtf2, bcur, NB,
                                    STRIDE);
    // ---- CSR build ----
    bucketA_k<<<tblocks, 256, 0, stream>>>(srcv, dstv, bcur, coarse, E, NB);
    bucketB_k<<<NB, 256, 0, stream>>>(coarse, bcur, rowstart, rowend, col, dinv, N,
                                      STRIDE);

    // layer 1: h = x@W1 (fp8)
    mfma_gemm_k<0, 1><<<gblocks, 256, 0, stream>>>(x, Wt1, nullptr, nullptr, nullptr,
                                                   nullptr, nullptr, nullptr, nullptr,
                                                   nullptr, bufA8, N);
    // conv1 + bn1 + relu -> bf16
    gather_k<<<wblocks, 256, 0, stream>>>(bufA8, rowstart, rowend, col, dinv, b1, g1,
                                          be1, m1, v1, bufB, N);
    // layer 2 GEMM: h@W2 (fp8)
    mfma_gemm_k<0, 0><<<gblocks, 256, 0, stream>>>(bufB, Wt2, nullptr, nullptr, nullptr,
                                                   nullptr, nullptr, nullptr, nullptr,
                                                   nullptr, bufA8, N);
    // conv2 + bn2 + relu -> bf16
    gather_k<<<wblocks, 256, 0, stream>>>(bufA8, rowstart, rowend, col, dinv, b2, g2,
                                          be2, m2, v2, bufB, N);
    // layer 3: h = relu(bn3(h@Wf1 + bf1)) -> bf16
    mfma_gemm_k<1, 0><<<gblocks, 256, 0, stream>>>(bufB, Wtf1, bf1, g3, be3, m3, v3,
                                                   nullptr, nullptr, nullptr, bufC, N);
    // layer 4 + head: h1 = relu(h@Wf2 + bf2) -> f32 d_out; pred = softplus(h1@Wo+bo)
    mfma_gemm_k<2, 0><<<gblocks, 256, 0, stream>>>(bufC, Wtf2, bf2, nullptr, nullptr,
                                                   nullptr, nullptr, Wo, bo, out_pred,
                                                   out_h1, N);
}

// Round 10
// 403.462 us; speedup vs baseline: 1.2559x; 1.1331x over previous
//
#include <hip/hip_runtime.h>
#include <math.h>

#define EPS_BN 1e-5f
#define MAXNB 512  // max coarse buckets (N <= 131072); also assumes N < 2^24

typedef __attribute__((ext_vector_type(8))) short bf16x8;
typedef __attribute__((ext_vector_type(4))) float f32x4;
typedef __attribute__((ext_vector_type(2))) float f32x2;

__device__ __forceinline__ ushort f2bf(float f) {
    uint u = __float_as_uint(f);
    u += 0x7FFF + ((u >> 16) & 1);  // RTN-even
    return (ushort)(u >> 16);
}
__device__ __forceinline__ float bf2f(uint h) {
    return __uint_as_float(h << 16);
}
__device__ __forceinline__ unsigned char f2fp8(float v) {
    uint q = __builtin_amdgcn_cvt_pk_fp8_f32(v, v, 0, false);
    return (unsigned char)(q & 0xff);
}

// ================= prep: 4 weight transposes (f32->bf16^T) + bcur init =================
__global__ __launch_bounds__(256) void prep_k(const float* __restrict__ W1,
                                              const float* __restrict__ W2,
                                              const float* __restrict__ W3,
                                              const float* __restrict__ W4,
                                              ushort* __restrict__ T1,
                                              ushort* __restrict__ T2,
                                              ushort* __restrict__ T3,
                                              ushort* __restrict__ T4,
                                              int* __restrict__ bcur, int NB, int stride) {
    if (blockIdx.x == 256) {
        for (int i = threadIdx.x; i < NB; i += 256) bcur[i] = i * stride;
        return;
    }
    int which = blockIdx.x >> 6;
    const float* W = (which == 0) ? W1 : (which == 1) ? W2 : (which == 2) ? W3 : W4;
    ushort* T = (which == 0) ? T1 : (which == 1) ? T2 : (which == 2) ? T3 : T4;
    int i = (blockIdx.x & 63) * 256 + threadIdx.x;  // < 16384
    int n = i >> 7, k = i & 127;
    T[n * 128 + k] = f2bf(W[k * 128 + n]);
}

// ================= bucketed CSR build (fixed-stride buckets) =================
// tile-ranked scatter; coarse entry packed: src | (dst&255)<<24
__global__ __launch_bounds__(256) void bucketA_k(const int* __restrict__ src,
                                                 const int* __restrict__ dst,
                                                 int* __restrict__ bcur,
                                                 int* __restrict__ coarse, int nE, int NB) {
    __shared__ int cnt[MAXNB];
    __shared__ int basix[MAXNB];
    const int tid = threadIdx.x;
    for (int i = tid; i < NB; i += 256) cnt[i] = 0;
    __syncthreads();
    int base = blockIdx.x * 4096;
    int es[16], ed[16], rk[16];
#pragma unroll
    for (int i = 0; i < 16; i++) {
        int e = base + i * 256 + tid;
        if (e < nE) {
            es[i] = src[e];
            ed[i] = dst[e];
            rk[i] = atomicAdd(&cnt[ed[i] >> 8], 1);
        } else {
            ed[i] = -1;
        }
    }
    __syncthreads();
    for (int i = tid; i < NB; i += 256)
        if (cnt[i]) basix[i] = atomicAdd(&bcur[i], cnt[i]);
    __syncthreads();
#pragma unroll
    for (int i = 0; i < 16; i++) {
        if (ed[i] >= 0)
            coarse[basix[ed[i] >> 8] + rk[i]] = es[i] | ((ed[i] & 255) << 24);
    }
}

// per-bucket exact CSR: rowstart/rowend/col/dinv; bucket b owns [b*stride, bcur[b])
__global__ __launch_bounds__(256) void bucketB_k(const int* __restrict__ coarse,
                                                 const int* __restrict__ bcur,
                                                 int* __restrict__ rowstart,
                                                 int* __restrict__ rowend,
                                                 int* __restrict__ col,
                                                 float* __restrict__ dinv, int N,
                                                 int stride) {
    __shared__ int cnt[256];
    __shared__ int s[256];
    __shared__ int cur[256];
    const int tid = threadIdx.x;
    const int b = blockIdx.x;
    const int beg = b * stride, end = bcur[b];
    cnt[tid] = 0;
    __syncthreads();
    for (int p = beg + tid; p < end; p += 256)
        atomicAdd(&cnt[((uint)coarse[p]) >> 24], 1);
    __syncthreads();
    int c = cnt[tid];
    s[tid] = c;
    __syncthreads();
    for (int off = 1; off < 256; off <<= 1) {
        int v = (tid >= off) ? s[tid - off] : 0;
        __syncthreads();
        s[tid] += v;
        __syncthreads();
    }
    int ex = s[tid] - c;
    int node = b * 256 + tid;
    if (node < N) {
        rowstart[node] = beg + ex;
        rowend[node] = beg + ex + c;
        dinv[node] = rsqrtf((float)c + 1.0f);  // +1 = self loop
    }
    cur[tid] = ex;
    __syncthreads();
    for (int p = beg + tid; p < end; p += 256) {
        int v = coarse[p];
        int r = atomicAdd(&cur[((uint)v) >> 24], 1);
        col[beg + r] = v & 0xFFFFFF;
    }
}

// ============ gather conv over pre-scaled fp8 rows hs = dinv[s]*(XW)[s] ============
// out = relu(bn(dd*(hs[d] + Sum_s hs[s]) + bias))
// 16 lanes per edge-row (8 ch/lane, uint2 = 8B), 4 edge-groups, 4-deep unroll
// => 16 edges in flight per wave (matched to mean degree ~16)
__device__ __forceinline__ void add8_fp8(float* acc, uint2 a) {
    f32x2 p;
    p = __builtin_amdgcn_cvt_pk_f32_fp8(a.x, false);
    acc[0] += p.x; acc[1] += p.y;
    p = __builtin_amdgcn_cvt_pk_f32_fp8(a.x, true);
    acc[2] += p.x; acc[3] += p.y;
    p = __builtin_amdgcn_cvt_pk_f32_fp8(a.y, false);
    acc[4] += p.x; acc[5] += p.y;
    p = __builtin_amdgcn_cvt_pk_f32_fp8(a.y, true);
    acc[6] += p.x; acc[7] += p.y;
}

__global__ __launch_bounds__(256) void gather_k(const unsigned char* __restrict__ h8,
                                                const int* __restrict__ rowstart,
                                                const int* __restrict__ rowend,
                                                const int* __restrict__ col,
                                                const float* __restrict__ dinv,
                                                const float* __restrict__ bias,
                                                const float* __restrict__ g,
                                                const float* __restrict__ be,
                                                const float* __restrict__ mn,
                                                const float* __restrict__ vr,
                                                ushort* __restrict__ out, int n) {
    int node = blockIdx.x * 4 + (threadIdx.x >> 6);
    if (node >= n) return;
    int lane = threadIdx.x & 63;
    int grp = lane >> 4;   // 0..3: edge slot
    int li = lane & 15;    // channel group: 8 ch
    int c = li * 8;
    int beg = rowstart[node], end = rowend[node];
    float acc[8] = {0.f, 0.f, 0.f, 0.f, 0.f, 0.f, 0.f, 0.f};

    if (grp == 0) {  // self loop: hs[d]
        uint2 rv = *(const uint2*)&h8[(size_t)node * 128 + c];
        add8_fp8(acc, rv);
    }

    int p = beg + grp;
    for (; p + 12 < end; p += 16) {  // 4 edges per group per iter = 16 edges/wave
        int s0 = __builtin_nontemporal_load(col + p);
        int s1 = __builtin_nontemporal_load(col + p + 4);
        int s2 = __builtin_nontemporal_load(col + p + 8);
        int s3 = __builtin_nontemporal_load(col + p + 12);
        uint2 a0 = *(const uint2*)&h8[(size_t)s0 * 128 + c];
        uint2 a1 = *(const uint2*)&h8[(size_t)s1 * 128 + c];
        uint2 a2 = *(const uint2*)&h8[(size_t)s2 * 128 + c];
        uint2 a3 = *(const uint2*)&h8[(size_t)s3 * 128 + c];
        add8_fp8(acc, a0);
        add8_fp8(acc, a1);
        add8_fp8(acc, a2);
        add8_fp8(acc, a3);
    }
    for (; p < end; p += 4) {
        int s0 = __builtin_nontemporal_load(col + p);
        uint2 a = *(const uint2*)&h8[(size_t)s0 * 128 + c];
        add8_fp8(acc, a);
    }
    // reduce the 4 edge-groups (lanes li, li+16, li+32, li+48 hold same channels)
#pragma unroll
    for (int j = 0; j < 8; j++) {
        acc[j] += __shfl_xor(acc[j], 16, 64);
        acc[j] += __shfl_xor(acc[j], 32, 64);
    }
    if (grp == 0) {
        float dd = dinv[node];
        uint r[4];
#pragma unroll
        for (int j = 0; j < 4; j++) {
            int cc = c + j * 2;
            float sc0 = g[cc] * rsqrtf(vr[cc] + EPS_BN);
            float sc1 = g[cc + 1] * rsqrtf(vr[cc + 1] + EPS_BN);
            float o0 = fmaxf((acc[j * 2] * dd + bias[cc] - mn[cc]) * sc0 + be[cc], 0.0f);
            float o1 = fmaxf((acc[j * 2 + 1] * dd + bias[cc + 1] - mn[cc + 1]) * sc1 + be[cc + 1], 0.0f);
            r[j] = (uint)f2bf(o0) | ((uint)f2bf(o1) << 16);
        }
        uint4 rv = {r[0], r[1], r[2], r[3]};
        *(uint4*)&out[(size_t)node * 128 + c] = rv;
    }
}

// ============ MFMA GEMM: Y = X(n,128) @ W(128,128), fused epilogues ============
// MODE 0: hs = dinv[row]*v -> fp8 e4m3   MODE 1: relu(bn(v+bias)) -> bf16
// MODE 2: relu(v+bias) -> f32, PLUS fused head: pred = softplus(h1 @ Wo + bo)
// F32IN: input X is f32 (converted to bf16 during LDS staging)
template <int MODE, int F32IN>
__global__ __launch_bounds__(256) void mfma_gemm_k(const void* __restrict__ Xin,
                                                   const ushort* __restrict__ Wt,
                                                   const float* __restrict__ dinvp,
                                                   const float* __restrict__ bias,
                                                   const float* __restrict__ g,
                                                   const float* __restrict__ be,
                                                   const float* __restrict__ mn,
                                                   const float* __restrict__ vr,
                                                   const float* __restrict__ Wo,
                                                   const float* __restrict__ bo,
                                                   float* __restrict__ pred,
                                                   void* __restrict__ Y, int nrows) {
    constexpr int LDK = 136;  // 128 + 8 pad
    __shared__ ushort sX[64 * LDK];
    __shared__ ushort sW[128 * LDK];
    __shared__ float red[64];
    __shared__ float sD[64];
    const int tid = threadIdx.x;
    const int row0 = blockIdx.x * 64;

#pragma unroll
    for (int i = 0; i < 8; i++) {
        int c = tid + i * 256;
        int r = c >> 4, o = c & 15;
        *(int4*)&sW[r * LDK + o * 8] = *(const int4*)&Wt[r * 128 + o * 8];
    }
    if (F32IN) {
        const float* Xf = (const float*)Xin;
#pragma unroll
        for (int i = 0; i < 8; i++) {
            int c = tid + i * 256;
            int r = c >> 5, o = c & 31;
            int rg = row0 + r;
            if (rg >= nrows) rg = nrows - 1;
            float4 v = *(const float4*)&Xf[(size_t)rg * 128 + o * 4];
            ushort4 u = {f2bf(v.x), f2bf(v.y), f2bf(v.z), f2bf(v.w)};
            *(ushort4*)&sX[r * LDK + o * 4] = u;
        }
    } else {
        const ushort* Xb = (const ushort*)Xin;
#pragma unroll
        for (int i = 0; i < 4; i++) {
            int c = tid + i * 256;
            int r = c >> 4, o = c & 15;
            int rg = row0 + r;
            if (rg >= nrows) rg = nrows - 1;
            *(int4*)&sX[r * LDK + o * 8] = *(const int4*)&Xb[(size_t)rg * 128 + o * 8];
        }
    }
    if (MODE == 2 && tid < 64) red[tid] = 0.0f;
    if (MODE == 0 && tid < 64) {
        int rg = row0 + tid;
        sD[tid] = dinvp[(rg < nrows) ? rg : (nrows - 1)];
    }
    __syncthreads();

    const int wave = tid >> 6, lane = tid & 63;
    const int rw = (wave >> 1) * 32;
    const int cw = (wave & 1) * 64;
    const int lm = lane & 15, lq = lane >> 4;

    f32x4 acc[2][4];
#pragma unroll
    for (int tr = 0; tr < 2; tr++)
#pragma unroll
        for (int tc = 0; tc < 4; tc++) acc[tr][tc] = (f32x4){0.f, 0.f, 0.f, 0.f};

#pragma unroll
    for (int ks = 0; ks < 4; ks++) {
        int kb = ks * 32 + lq * 8;
        bf16x8 a[2], b[4];
#pragma unroll
        for (int tr = 0; tr < 2; tr++)
            a[tr] = *(bf16x8*)&sX[(rw + tr * 16 + lm) * LDK + kb];
#pragma unroll
        for (int tc = 0; tc < 4; tc++)
            b[tc] = *(bf16x8*)&sW[(cw + tc * 16 + lm) * LDK + kb];
#pragma unroll
        for (int tr = 0; tr < 2; tr++)
#pragma unroll
            for (int tc = 0; tc < 4; tc++)
                acc[tr][tc] = __builtin_amdgcn_mfma_f32_16x16x32_bf16(a[tr], b[tc],
                                                                      acc[tr][tc], 0, 0, 0);
    }

    float part[8];
    if (MODE == 2) {
#pragma unroll
        for (int i = 0; i < 8; i++) part[i] = 0.0f;
    }
#pragma unroll
    for (int tc = 0; tc < 4; tc++) {
        int c = cw + tc * 16 + lm;
        float psc, psh;
        if (MODE == 1) {
            float sc = g[c] * rsqrtf(vr[c] + EPS_BN);
            psc = sc;
            psh = be[c] + (bias[c] - mn[c]) * sc;
        } else if (MODE == 2) {
            psc = 1.0f;
            psh = bias[c];
        } else {
            psc = 1.0f;
            psh = 0.0f;
        }
        float woc = (MODE == 2) ? Wo[c] : 0.0f;
#pragma unroll
        for (int tr = 0; tr < 2; tr++) {
#pragma unroll
            for (int r = 0; r < 4; r++) {
                int lrow = rw + tr * 16 + lq * 4 + r;
                int row = row0 + lrow;
                if (row < nrows) {
                    float v = acc[tr][tc][r];
                    if (MODE == 0) {
                        ((unsigned char*)Y)[(size_t)row * 128 + c] = f2fp8(v * sD[lrow]);
                    } else if (MODE == 1) {
                        v = fmaxf(v * psc + psh, 0.0f);
                        ((ushort*)Y)[(size_t)row * 128 + c] = f2bf(v);
                    } else {
                        v = fmaxf(v + psh, 0.0f);
                        ((float*)Y)[(size_t)row * 128 + c] = v;
                        part[tr * 4 + r] = fmaf(v, woc, part[tr * 4 + r]);
                    }
                }
            }
        }
    }
    if (MODE == 2) {
#pragma unroll
        for (int tr = 0; tr < 2; tr++)
#pragma unroll
            for (int r = 0; r < 4; r++)
                atomicAdd(&red[rw + tr * 16 + lq * 4 + r], part[tr * 4 + r]);
        __syncthreads();
        if (tid < 64) {
            int row = row0 + tid;
            if (row < nrows) {
                float xv = red[tid] + bo[0];
                pred[row] = fmaxf(xv, 0.0f) + log1pf(expf(-fabsf(xv)));  // softplus
            }
        }
    }
}

extern "C" void kernel_launch(void* const* d_in, const int* in_sizes, int n_in,
                              void* d_out, int out_size, void* d_ws, size_t ws_size,
                              hipStream_t stream) {
    const float* x = (const float*)d_in[0];
    const int* ei = (const int*)d_in[1];
    const int N = in_sizes[0] / 128;
    const int E = in_sizes[1] / 2;
    const int* srcv = ei;
    const int* dstv = ei + E;
    const float* W1 = (const float*)d_in[2];  const float* b1 = (const float*)d_in[3];
    const float* W2 = (const float*)d_in[4];  const float* b2 = (const float*)d_in[5];
    const float* Wf1 = (const float*)d_in[6]; const float* bf1 = (const float*)d_in[7];
    const float* Wf2 = (const float*)d_in[8]; const float* bf2 = (const float*)d_in[9];
    const float* Wo = (const float*)d_in[10]; const float* bo = (const float*)d_in[11];
    const float* g1 = (const float*)d_in[12], *be1 = (const float*)d_in[13],
               *m1 = (const float*)d_in[14], *v1 = (const float*)d_in[15];
    const float* g2 = (const float*)d_in[16], *be2 = (const float*)d_in[17],
               *m2 = (const float*)d_in[18], *v2 = (const float*)d_in[19];
    const float* g3 = (const float*)d_in[20], *be3 = (const float*)d_in[21],
               *m3 = (const float*)d_in[22], *v3 = (const float*)d_in[23];

    // ---- workspace carve-up ----
    char* ws = (char*)d_ws;
    size_t off = 0;
    auto carve = [&](size_t bytes) {
        char* p = ws + off;
        off = (off + bytes + 255) & ~(size_t)255;
        return p;
    };
    const int NB = (N + 255) >> 8;
    const int STRIDE = ((E / NB + 511) + 255) & ~255;  // mean + ~8 sigma slack
    int* bcur = (int*)carve((size_t)MAXNB * 4);
    int* rowstart = (int*)carve((size_t)N * 4);
    int* rowend = (int*)carve((size_t)N * 4);
    int* col = (int*)carve((size_t)NB * STRIDE * 4);
    int* coarse = (int*)carve((size_t)NB * STRIDE * 4);
    float* dinv = (float*)carve((size_t)N * 4);
    unsigned char* bufA8 = (unsigned char*)carve((size_t)N * 128);  // fp8 hs
    ushort* bufB = (ushort*)carve((size_t)N * 128 * 2);             // bf16
    ushort* bufC = (ushort*)carve((size_t)N * 128 * 2);             // bf16
    ushort* Wt1 = (ushort*)carve(128 * 128 * 2);
    ushort* Wt2 = (ushort*)carve(128 * 128 * 2);
    ushort* Wtf1 = (ushort*)carve(128 * 128 * 2);
    ushort* Wtf2 = (ushort*)carve(128 * 128 * 2);

    float* out_pred = (float*)d_out;
    float* out_h1 = out_pred + N;

    const int gblocks = (N + 63) / 64;
    const int tblocks = (E + 4095) / 4096;
    const int wblocks = (N + 3) / 4;

    // ---- prep (weights + bcur) ----
    prep_k<<<257, 256, 0, stream>>>(W1, W2, Wf1, Wf2, Wt1, Wt2, Wtf1, Wtf2, bcur, NB,
                                    STRIDE);
    // ---- CSR build ----
    bucketA_k<<<tblocks, 256, 0, stream>>>(srcv, dstv, bcur, coarse, E, NB);
    bucketB_k<<<NB, 256, 0, stream>>>(coarse, bcur, rowstart, rowend, col, dinv, N,
                                      STRIDE);

    // layer 1: hs1 = dinv*(x@W1) (fp8)
    mfma_gemm_k<0, 1><<<gblocks, 256, 0, stream>>>(x, Wt1, dinv, nullptr, nullptr,
                                                   nullptr, nullptr, nullptr, nullptr,
                                                   nullptr, nullptr, bufA8, N);
    // conv1 + bn1 + relu -> bf16
    gather_k<<<wblocks, 256, 0, stream>>>(bufA8, rowstart, rowend, col, dinv, b1, g1,
                                          be1, m1, v1, bufB, N);
    // layer 2 GEMM: hs2 = dinv*(h@W2) (fp8)
    mfma_gemm_k<0, 0><<<gblocks, 256, 0, stream>>>(bufB, Wt2, dinv, nullptr, nullptr,
                                                   nullptr, nullptr, nullptr, nullptr,
                                                   nullptr, nullptr, bufA8, N);
    // conv2 + bn2 + relu -> bf16
    gather_k<<<wblocks, 256, 0, stream>>>(bufA8, rowstart, rowend, col, dinv, b2, g2,
                                          be2, m2, v2, bufB, N);
    // layer 3: h = relu(bn3(h@Wf1 + bf1)) -> bf16
    mfma_gemm_k<1, 0><<<gblocks, 256, 0, stream>>>(bufB, Wtf1, nullptr, bf1, g3, be3, m3,
                                                   v3, nullptr, nullptr, nullptr, bufC, N);
    // layer 4 + head: h1 = relu(h@Wf2 + bf2) -> f32 d_out; pred = softplus(h1@Wo+bo)
    mfma_gemm_k<2, 0><<<gblocks, 256, 0, stream>>>(bufC, Wtf2, nullptr, bf2, nullptr,
                                                   nullptr, nullptr, nullptr, Wo, bo,
                                                   out_pred, out_h1, N);
}